// Round 3
// baseline (722.385 us; speedup 1.0000x reference)
//
#include <hip/hip_runtime.h>
#include <hip/hip_fp16.h>
#include <math.h>

#define NAB 128
#define NG 50
#define TK 1024      // ef interpolation grid points
#define BN 128       // nodes per scan block

__device__ __forceinline__ float sspf(float x) {
  float t = __expf(-fabsf(x));
  return fmaxf(x, 0.0f) + __logf(1.0f + t) - 0.69314718055994531f;
}

// ---------------------------------------------------------------------------
// C[M,128] = A[M,128] @ W[128,128] (+ bias).
// mode: 0 = fp32 store, 1 = fp32 + ssp store, 2 = fp16 store (fused rf cast)
__global__ __launch_bounds__(128)
void gemm128(const float* __restrict__ A, const float* __restrict__ W,
             const float* __restrict__ bias, void* __restrict__ Cout,
             int M, int mode) {
  __shared__ float Al[32 * 128];
  const int tid = threadIdx.x;
  const int r0 = blockIdx.x * 32;
  const int rows = min(32, M - r0);

  {
    const float4* A4 = (const float4*)(A + (size_t)r0 * NAB);
    float4* Al4 = (float4*)Al;
    for (int f = tid; f < rows * 32; f += 128) Al4[f] = A4[f];
  }
  __syncthreads();

  const int c = tid & 31;
  const int gq = tid >> 5;
  float acc[8][4];
#pragma unroll
  for (int j = 0; j < 8; ++j) {
    acc[j][0] = 0.f; acc[j][1] = 0.f; acc[j][2] = 0.f; acc[j][3] = 0.f;
  }
  const float4* W4 = (const float4*)W;
  for (int i = 0; i < 128; i += 4) {
    float4 w0 = W4[(i + 0) * 32 + c];
    float4 w1 = W4[(i + 1) * 32 + c];
    float4 w2 = W4[(i + 2) * 32 + c];
    float4 w3 = W4[(i + 3) * 32 + c];
#pragma unroll
    for (int j = 0; j < 8; ++j) {
      float4 av = *(const float4*)&Al[(gq * 8 + j) * 128 + i];
      acc[j][0] += av.x * w0.x + av.y * w1.x + av.z * w2.x + av.w * w3.x;
      acc[j][1] += av.x * w0.y + av.y * w1.y + av.z * w2.y + av.w * w3.y;
      acc[j][2] += av.x * w0.z + av.y * w1.z + av.z * w2.z + av.w * w3.z;
      acc[j][3] += av.x * w0.w + av.y * w1.w + av.z * w2.w + av.w * w3.w;
    }
  }
  float4 bv = make_float4(0.f, 0.f, 0.f, 0.f);
  if (bias) bv = *(const float4*)&bias[4 * c];
#pragma unroll
  for (int j = 0; j < 8; ++j) {
    int row = gq * 8 + j;
    if (row < rows) {
      float4 o;
      o.x = acc[j][0] + bv.x;
      o.y = acc[j][1] + bv.y;
      o.z = acc[j][2] + bv.z;
      o.w = acc[j][3] + bv.w;
      if (mode == 1) { o.x = sspf(o.x); o.y = sspf(o.y); o.z = sspf(o.z); o.w = sspf(o.w); }
      if (mode == 2) {
        __half2 h01 = __floats2half2_rn(o.x, o.y);
        __half2 h23 = __floats2half2_rn(o.z, o.w);
        uint2 u;
        u.x = *(unsigned*)&h01;
        u.y = *(unsigned*)&h23;
        *(uint2*)((__half*)Cout + (size_t)(r0 + row) * NAB + 4 * c) = u;
      } else {
        *(float4*)((float*)Cout + (size_t)(r0 + row) * NAB + 4 * c) = o;
      }
    }
  }
}

// ---------------------------------------------------------------------------
// Build fp16 (base, delta) lerp table (unchanged from R2).
__global__ __launch_bounds__(128)
void build_tp(const float* __restrict__ W1, const float* __restrict__ b1,
              const float* __restrict__ W2, const float* __restrict__ b2,
              uint2* __restrict__ Th) {
  __shared__ float h0[NG], h1[NG], e0[NAB], e1[NAB];
  const int k = blockIdx.x;       // 0 .. TK-2
  const int tid = threadIdx.x;
  constexpr float width = 5.0f / 49.0f;
  constexpr float coeff = -0.5f / (width * width);
  const float x0 = (float)k * (5.0f / (float)(TK - 1));
  const float x1 = (float)(k + 1) * (5.0f / (float)(TK - 1));

  if (tid < NG) {
    float a0 = b1[tid], a1 = b1[tid];
    for (int i = 0; i < NG; ++i) {
      float w = W1[i * NG + tid];
      float d0 = x0 - i * width;
      float d1 = x1 - i * width;
      a0 = __fmaf_rn(__expf(coeff * d0 * d0), w, a0);
      a1 = __fmaf_rn(__expf(coeff * d1 * d1), w, a1);
    }
    h0[tid] = sspf(a0);
    h1[tid] = sspf(a1);
  }
  __syncthreads();
  float f0 = b2[tid], f1 = b2[tid];
#pragma unroll 10
  for (int i = 0; i < NG; ++i) {
    float w = W2[i * NAB + tid];
    f0 = __fmaf_rn(h0[i], w, f0);
    f1 = __fmaf_rn(h1[i], w, f1);
  }
  e0[tid] = f0;
  e1[tid] = f1;
  __syncthreads();
  if (tid < 64) {
    float b0 = e0[2 * tid],      d0 = e1[2 * tid]     - e0[2 * tid];
    float b1v = e0[2 * tid + 1], d1 = e1[2 * tid + 1] - e0[2 * tid + 1];
    __half2 p0 = __floats2half2_rn(b0, d0);
    __half2 p1 = __floats2half2_rn(b1v, d1);
    uint2 u;
    u.x = *(unsigned*)&p0;
    u.y = *(unsigned*)&p1;
    Th[(size_t)k * 64 + tid] = u;
  }
}

// ---------------------------------------------------------------------------
// Pass 1 of counting sort: per-node histogram. 3.2M atomics over 50000
// counters -> ~64 per address, no serialization chains.
__global__ __launch_bounds__(256)
void hist_kernel(const int* __restrict__ a, int* __restrict__ nhist, int E) {
  int i = blockIdx.x * 256 + threadIdx.x;
  if (i >= 2 * E) return;
  int tgt = (i < E) ? a[2 * i + 1] : a[2 * (i - E)];
  atomicAdd(&nhist[tgt], 1);
}

// ---------------------------------------------------------------------------
// Pass 2a: per-128-node-block totals.
__global__ __launch_bounds__(128)
void scan_breduce(const int* __restrict__ nhist, int* __restrict__ btot, int N) {
  __shared__ int s[128];
  int t = threadIdx.x;
  int n = blockIdx.x * 128 + t;
  s[t] = (n < N) ? nhist[n] : 0;
  __syncthreads();
  for (int d = 64; d > 0; d >>= 1) {
    if (t < d) s[t] += s[t + d];
    __syncthreads();
  }
  if (t == 0) btot[blockIdx.x] = s[0];
}

// ---------------------------------------------------------------------------
// Pass 2b: exclusive scan of block totals (NB <= 512), single block.
__global__ __launch_bounds__(512)
void scan_bbase(const int* __restrict__ btot, int* __restrict__ bbase, int NB) {
  __shared__ int s[512];
  int t = threadIdx.x;
  int v = (t < NB) ? btot[t] : 0;
  s[t] = v;
  __syncthreads();
  for (int d = 1; d < 512; d <<= 1) {
    int u = (t >= d) ? s[t - d] : 0;
    __syncthreads();
    s[t] += u;
    __syncthreads();
  }
  if (t < NB) bbase[t] = s[t] - v;   // exclusive prefix
}

// ---------------------------------------------------------------------------
// Pass 2c: per-node CSR offsets: nstart/ncur/nend.
__global__ __launch_bounds__(128)
void scan_nstart(const int* __restrict__ nhist, const int* __restrict__ bbase,
                 int* __restrict__ nstart, int* __restrict__ ncur,
                 int* __restrict__ nend, int N) {
  __shared__ int s[128];
  int t = threadIdx.x;
  int n = blockIdx.x * 128 + t;
  int h = (n < N) ? nhist[n] : 0;
  s[t] = h;
  __syncthreads();
  for (int d = 1; d < 128; d <<= 1) {
    int u = (t >= d) ? s[t - d] : 0;
    __syncthreads();
    s[t] += u;
    __syncthreads();
  }
  if (n < N) {
    int st = bbase[blockIdx.x] + s[t] - h;
    nstart[n] = st;
    ncur[n]   = st;
    nend[n]   = st + h;
  }
}

// ---------------------------------------------------------------------------
// Pass 3: scatter directly to node-sorted position. ~64 atomics/cursor.
// item = (src, k<<16 | half(f)). No local_sort needed afterwards.
__global__ __launch_bounds__(256)
void scatter_kernel(const int* __restrict__ a, const float* __restrict__ e,
                    int* __restrict__ ncur, int2* __restrict__ items, int E) {
  int i = blockIdx.x * 256 + threadIdx.x;
  if (i >= 2 * E) return;
  int edge, tgt, src;
  if (i < E) {
    edge = i; src = a[2 * i]; tgt = a[2 * i + 1];
  } else {
    edge = i - E; tgt = a[2 * edge]; src = a[2 * edge + 1];
  }
  const float scale = (float)(TK - 1) / 5.0f;
  float x = e[edge] * scale;
  int k = min((int)x, TK - 2);
  float f = x - (float)k;
  unsigned fh = __half_as_ushort(__float2half_rn(f));
  int pos = atomicAdd(&ncur[tgt], 1);
  items[pos] = make_int2(src, (k << 16) | (int)fh);
}

// ---------------------------------------------------------------------------
// Pull: one WAVE per node, register accumulator, no atomics.
// SGPR gather bases via readfirstlane; fp16 (base,delta) table -> 8B/lane.
__global__ __launch_bounds__(256)
void pull_kernel(const int* __restrict__ nstart, const int* __restrict__ nend,
                 const int2* __restrict__ items, const __half* __restrict__ rfh,
                 const uint2* __restrict__ Th, float* __restrict__ agg, int N) {
  const int wv = __builtin_amdgcn_readfirstlane(threadIdx.x >> 6);
  const int n = blockIdx.x * 4 + wv;
  if (n >= N) return;
  const int l = threadIdx.x & 63;
  int j  = nstart[n];
  const int j1 = nend[n];
  float a0 = 0.f, a1 = 0.f;

  for (; j + 4 <= j1; j += 4) {
    int2 p0 = items[j + 0];
    int2 p1 = items[j + 1];
    int2 p2 = items[j + 2];
    int2 p3 = items[j + 3];
    int sx0 = __builtin_amdgcn_readfirstlane(p0.x);
    int sy0 = __builtin_amdgcn_readfirstlane(p0.y);
    int sx1 = __builtin_amdgcn_readfirstlane(p1.x);
    int sy1 = __builtin_amdgcn_readfirstlane(p1.y);
    int sx2 = __builtin_amdgcn_readfirstlane(p2.x);
    int sy2 = __builtin_amdgcn_readfirstlane(p2.y);
    int sx3 = __builtin_amdgcn_readfirstlane(p3.x);
    int sy3 = __builtin_amdgcn_readfirstlane(p3.y);
    const uint2* tp0 = Th + ((size_t)(sy0 >> 16) << 6);
    const uint2* tp1 = Th + ((size_t)(sy1 >> 16) << 6);
    const uint2* tp2 = Th + ((size_t)(sy2 >> 16) << 6);
    const uint2* tp3 = Th + ((size_t)(sy3 >> 16) << 6);
    const __half* rp0 = rfh + ((size_t)(sx0 & 0xffff) << 7);
    const __half* rp1 = rfh + ((size_t)(sx1 & 0xffff) << 7);
    const __half* rp2 = rfh + ((size_t)(sx2 & 0xffff) << 7);
    const __half* rp3 = rfh + ((size_t)(sx3 & 0xffff) << 7);
    uint2 t0 = tp0[l];
    uint2 t1 = tp1[l];
    uint2 t2 = tp2[l];
    uint2 t3 = tp3[l];
    unsigned q0 = *(const unsigned*)(rp0 + 2 * l);
    unsigned q1 = *(const unsigned*)(rp1 + 2 * l);
    unsigned q2 = *(const unsigned*)(rp2 + 2 * l);
    unsigned q3 = *(const unsigned*)(rp3 + 2 * l);
    float f0 = __half2float(__ushort_as_half((unsigned short)sy0));
    float f1 = __half2float(__ushort_as_half((unsigned short)sy1));
    float f2 = __half2float(__ushort_as_half((unsigned short)sy2));
    float f3 = __half2float(__ushort_as_half((unsigned short)sy3));
    float2 r0 = __half22float2(*(const __half2*)&q0);
    float2 r1 = __half22float2(*(const __half2*)&q1);
    float2 r2 = __half22float2(*(const __half2*)&q2);
    float2 r3 = __half22float2(*(const __half2*)&q3);
    {
      float2 b0 = __half22float2(*(const __half2*)&t0.x);
      float2 c0 = __half22float2(*(const __half2*)&t0.y);
      a0 = __fmaf_rn(r0.x, __fmaf_rn(f0, b0.y, b0.x), a0);
      a1 = __fmaf_rn(r0.y, __fmaf_rn(f0, c0.y, c0.x), a1);
    }
    {
      float2 b1 = __half22float2(*(const __half2*)&t1.x);
      float2 c1 = __half22float2(*(const __half2*)&t1.y);
      a0 = __fmaf_rn(r1.x, __fmaf_rn(f1, b1.y, b1.x), a0);
      a1 = __fmaf_rn(r1.y, __fmaf_rn(f1, c1.y, c1.x), a1);
    }
    {
      float2 b2 = __half22float2(*(const __half2*)&t2.x);
      float2 c2 = __half22float2(*(const __half2*)&t2.y);
      a0 = __fmaf_rn(r2.x, __fmaf_rn(f2, b2.y, b2.x), a0);
      a1 = __fmaf_rn(r2.y, __fmaf_rn(f2, c2.y, c2.x), a1);
    }
    {
      float2 b3 = __half22float2(*(const __half2*)&t3.x);
      float2 c3 = __half22float2(*(const __half2*)&t3.y);
      a0 = __fmaf_rn(r3.x, __fmaf_rn(f3, b3.y, b3.x), a0);
      a1 = __fmaf_rn(r3.y, __fmaf_rn(f3, c3.y, c3.x), a1);
    }
  }
  for (; j < j1; ++j) {
    int2 p = items[j];
    int sx = __builtin_amdgcn_readfirstlane(p.x);
    int sy = __builtin_amdgcn_readfirstlane(p.y);
    const uint2* tp = Th + ((size_t)(sy >> 16) << 6);
    const __half* rp = rfh + ((size_t)(sx & 0xffff) << 7);
    uint2 tv = tp[l];
    unsigned qq = *(const unsigned*)(rp + 2 * l);
    float fr = __half2float(__ushort_as_half((unsigned short)sy));
    float2 rv = __half22float2(*(const __half2*)&qq);
    float2 bb = __half22float2(*(const __half2*)&tv.x);
    float2 cc = __half22float2(*(const __half2*)&tv.y);
    a0 = __fmaf_rn(rv.x, __fmaf_rn(fr, bb.y, bb.x), a0);
    a1 = __fmaf_rn(rv.y, __fmaf_rn(fr, cc.y, cc.x), a1);
  }
  float2 o; o.x = a0; o.y = a1;
  *(float2*)&agg[((size_t)n << 7) + 2 * l] = o;
}

// ---------------------------------------------------------------------------
extern "C" void kernel_launch(void* const* d_in, const int* in_sizes, int n_in,
                              void* d_out, int out_size, void* d_ws, size_t ws_size,
                              hipStream_t stream) {
  const float* r     = (const float*)d_in[0];
  const float* e     = (const float*)d_in[1];
  const int*   a     = (const int*)d_in[2];
  const float* W_df1 = (const float*)d_in[3];
  const float* b_df1 = (const float*)d_in[4];
  const float* W_df2 = (const float*)d_in[5];
  const float* b_df2 = (const float*)d_in[6];
  const float* W_af  = (const float*)d_in[7];
  const float* W_d1  = (const float*)d_in[8];
  const float* b_d1  = (const float*)d_in[9];
  const float* W_d2  = (const float*)d_in[10];
  const float* b_d2  = (const float*)d_in[11];

  const int N = in_sizes[0] / NAB;
  const int E = in_sizes[1];
  const int H = 2 * E;
  const int NB = (N + BN - 1) / BN;   // 391 scan blocks

  // workspace layout (~65 MB). shared region: items [scatter->pull], then
  // t1 [gemm6->gemm7] — strictly sequential lifetimes.
  char* base = (char*)d_ws;
  size_t items_bytes = (size_t)H * sizeof(int2);        // 25.6 MB exact
  size_t t1_bytes = (size_t)N * NAB * sizeof(float);    // 25.6 MB
  size_t shared_bytes = items_bytes > t1_bytes ? items_bytes : t1_bytes;
  int2*   items  = (int2*)base;                         // first life
  float*  t1     = (float*)base;                        // second life
  float*  agg    = (float*)(base + shared_bytes);       // N*128 fp32
  __half* rfh    = (__half*)(agg + (size_t)N * NAB);    // N*128 fp16
  uint2*  Th     = (uint2*)(rfh + (size_t)N * NAB);     // (TK-1)*64*8B
  int*    nhist  = (int*)(Th + (size_t)(TK - 1) * 64);  // N
  int*    ncur   = nhist + N;                           // N
  int*    nstart = ncur + N;                            // N
  int*    nend   = nstart + N;                          // N
  int*    btot   = nend + N;                            // NB
  int*    bbase  = btot + NB;                           // NB

  const int gblocks = (N + 31) / 32;
  const int hblocks = (H + 255) / 256;

  // 1) fp16 (base,delta) ef lerp table
  build_tp<<<TK - 1, 128, 0, stream>>>(W_df1, b_df1, W_df2, b_df2, Th);
  // 2) rfh = fp16(r @ W_af) — fused cast epilogue
  gemm128<<<gblocks, 128, 0, stream>>>(r, W_af, nullptr, rfh, N, 2);
  // 3) per-node histogram
  hipMemsetAsync(nhist, 0, (size_t)N * sizeof(int), stream);
  hist_kernel<<<hblocks, 256, 0, stream>>>(a, nhist, E);
  // 4) CSR offsets via 3-level scan (all tiny)
  scan_breduce<<<NB, 128, 0, stream>>>(nhist, btot, N);
  scan_bbase<<<1, 512, 0, stream>>>(btot, bbase, NB);
  scan_nstart<<<NB, 128, 0, stream>>>(nhist, bbase, nstart, ncur, nend, N);
  // 5) direct node-sorted scatter (replaces bucket scatter + local_sort)
  scatter_kernel<<<hblocks, 256, 0, stream>>>(a, e, ncur, items, E);
  // 6) wave-per-node pull (SGPR gather bases, fp16 rf, fp16 base/delta table)
  pull_kernel<<<(N + 3) / 4, 256, 0, stream>>>(nstart, nend, items, rfh, Th, agg, N);
  // 7) t1 = ssp(agg @ W_d1 + b_d1)
  gemm128<<<gblocks, 128, 0, stream>>>(agg, W_d1, b_d1, t1, N, 1);
  // 8) out = t1 @ W_d2 + b_d2
  gemm128<<<gblocks, 128, 0, stream>>>(t1, W_d2, b_d2, d_out, N, 0);
}

// Round 4
// 614.366 us; speedup vs baseline: 1.1758x; 1.1758x over previous
//
#include <hip/hip_runtime.h>
#include <hip/hip_fp16.h>
#include <math.h>

#define NAB 128
#define NG 50
#define TK 1024      // ef interpolation grid points
#define BN 32        // nodes per bucket (R4: 128 -> 32, 4x shorter atomic chains)
#define CAP 2432     // slot capacity per bucket (avg 2048, +8.5 sigma)
#define CPAD 16      // ints per bucket cursor (own 64B line)

__device__ __forceinline__ float sspf(float x) {
  float t = __expf(-fabsf(x));
  return fmaxf(x, 0.0f) + __logf(1.0f + t) - 0.69314718055994531f;
}

// ---------------------------------------------------------------------------
// C[M,128] = A[M,128] @ W[128,128] (+ bias).
// mode: 0 = fp32 store, 1 = fp32 + ssp store, 2 = fp16 store (fused rf cast)
__global__ __launch_bounds__(128)
void gemm128(const float* __restrict__ A, const float* __restrict__ W,
             const float* __restrict__ bias, void* __restrict__ Cout,
             int M, int mode) {
  __shared__ float Al[32 * 128];
  const int tid = threadIdx.x;
  const int r0 = blockIdx.x * 32;
  const int rows = min(32, M - r0);

  {
    const float4* A4 = (const float4*)(A + (size_t)r0 * NAB);
    float4* Al4 = (float4*)Al;
    for (int f = tid; f < rows * 32; f += 128) Al4[f] = A4[f];
  }
  __syncthreads();

  const int c = tid & 31;
  const int gq = tid >> 5;
  float acc[8][4];
#pragma unroll
  for (int j = 0; j < 8; ++j) {
    acc[j][0] = 0.f; acc[j][1] = 0.f; acc[j][2] = 0.f; acc[j][3] = 0.f;
  }
  const float4* W4 = (const float4*)W;
  for (int i = 0; i < 128; i += 4) {
    float4 w0 = W4[(i + 0) * 32 + c];
    float4 w1 = W4[(i + 1) * 32 + c];
    float4 w2 = W4[(i + 2) * 32 + c];
    float4 w3 = W4[(i + 3) * 32 + c];
#pragma unroll
    for (int j = 0; j < 8; ++j) {
      float4 av = *(const float4*)&Al[(gq * 8 + j) * 128 + i];
      acc[j][0] += av.x * w0.x + av.y * w1.x + av.z * w2.x + av.w * w3.x;
      acc[j][1] += av.x * w0.y + av.y * w1.y + av.z * w2.y + av.w * w3.y;
      acc[j][2] += av.x * w0.z + av.y * w1.z + av.z * w2.z + av.w * w3.z;
      acc[j][3] += av.x * w0.w + av.y * w1.w + av.z * w2.w + av.w * w3.w;
    }
  }
  float4 bv = make_float4(0.f, 0.f, 0.f, 0.f);
  if (bias) bv = *(const float4*)&bias[4 * c];
#pragma unroll
  for (int j = 0; j < 8; ++j) {
    int row = gq * 8 + j;
    if (row < rows) {
      float4 o;
      o.x = acc[j][0] + bv.x;
      o.y = acc[j][1] + bv.y;
      o.z = acc[j][2] + bv.z;
      o.w = acc[j][3] + bv.w;
      if (mode == 1) { o.x = sspf(o.x); o.y = sspf(o.y); o.z = sspf(o.z); o.w = sspf(o.w); }
      if (mode == 2) {
        __half2 h01 = __floats2half2_rn(o.x, o.y);
        __half2 h23 = __floats2half2_rn(o.z, o.w);
        uint2 u;
        u.x = *(unsigned*)&h01;
        u.y = *(unsigned*)&h23;
        *(uint2*)((__half*)Cout + (size_t)(r0 + row) * NAB + 4 * c) = u;
      } else {
        *(float4*)((float*)Cout + (size_t)(r0 + row) * NAB + 4 * c) = o;
      }
    }
  }
}

// ---------------------------------------------------------------------------
// Build fp16 (base, delta) lerp table (unchanged from R2).
__global__ __launch_bounds__(128)
void build_tp(const float* __restrict__ W1, const float* __restrict__ b1,
              const float* __restrict__ W2, const float* __restrict__ b2,
              uint2* __restrict__ Th) {
  __shared__ float h0[NG], h1[NG], e0[NAB], e1[NAB];
  const int k = blockIdx.x;       // 0 .. TK-2
  const int tid = threadIdx.x;
  constexpr float width = 5.0f / 49.0f;
  constexpr float coeff = -0.5f / (width * width);
  const float x0 = (float)k * (5.0f / (float)(TK - 1));
  const float x1 = (float)(k + 1) * (5.0f / (float)(TK - 1));

  if (tid < NG) {
    float a0 = b1[tid], a1 = b1[tid];
    for (int i = 0; i < NG; ++i) {
      float w = W1[i * NG + tid];
      float d0 = x0 - i * width;
      float d1 = x1 - i * width;
      a0 = __fmaf_rn(__expf(coeff * d0 * d0), w, a0);
      a1 = __fmaf_rn(__expf(coeff * d1 * d1), w, a1);
    }
    h0[tid] = sspf(a0);
    h1[tid] = sspf(a1);
  }
  __syncthreads();
  float f0 = b2[tid], f1 = b2[tid];
#pragma unroll 10
  for (int i = 0; i < NG; ++i) {
    float w = W2[i * NAB + tid];
    f0 = __fmaf_rn(h0[i], w, f0);
    f1 = __fmaf_rn(h1[i], w, f1);
  }
  e0[tid] = f0;
  e1[tid] = f1;
  __syncthreads();
  if (tid < 64) {
    float b0 = e0[2 * tid],      d0 = e1[2 * tid]     - e0[2 * tid];
    float b1v = e0[2 * tid + 1], d1 = e1[2 * tid + 1] - e0[2 * tid + 1];
    __half2 p0 = __floats2half2_rn(b0, d0);
    __half2 p1 = __floats2half2_rn(b1v, d1);
    uint2 u;
    u.x = *(unsigned*)&p0;
    u.y = *(unsigned*)&p1;
    Th[(size_t)k * 64 + tid] = u;
  }
}

// ---------------------------------------------------------------------------
// Scatter both directions of each edge into 32-node bucket slots.
// One thread per EDGE: one int2 load, (k,f) computed once, two atomics.
// item = (gather_src | node_local<<16, k<<16 | half(f)).
__global__ __launch_bounds__(256)
void bscatter_kernel(const int2* __restrict__ a2, const float* __restrict__ e,
                     int* __restrict__ bcur, int2* __restrict__ items, int E) {
  int i = blockIdx.x * 256 + threadIdx.x;
  if (i >= E) return;
  int2 p = a2[i];                // (src, tgt)
  const float scale = (float)(TK - 1) / 5.0f;
  float x = e[i] * scale;
  int k = min((int)x, TK - 2);
  float f = x - (float)k;
  int payload = (k << 16) | (int)__half_as_ushort(__float2half_rn(f));
  // direction 1: accumulates into node tgt, gathers rf[src]
  {
    int b = p.y >> 5;
    int pos = atomicAdd(&bcur[b * CPAD], 1);
    if (pos < CAP)
      items[(size_t)b * CAP + pos] = make_int2(p.x | ((p.y & 31) << 16), payload);
  }
  // direction 2: accumulates into node src, gathers rf[tgt]
  {
    int b = p.x >> 5;
    int pos = atomicAdd(&bcur[b * CPAD], 1);
    if (pos < CAP)
      items[(size_t)b * CAP + pos] = make_int2(p.y | ((p.x & 31) << 16), payload);
  }
}

// ---------------------------------------------------------------------------
// Per-bucket counting sort (in LDS) -> items in node order + CSR (BN=32).
__global__ __launch_bounds__(256)
void local_sort(const int* __restrict__ bcur, int2* __restrict__ items,
                int* __restrict__ nstart, int* __restrict__ nend, int N) {
  __shared__ int2 lit[CAP];
  __shared__ int bin[BN], cur[BN], scn[BN];
  const int b = blockIdx.x;
  const int tid = threadIdx.x;
  const int cnt = min(bcur[b * CPAD], CAP);
  const size_t base = (size_t)b * CAP;

  for (int i = tid; i < cnt; i += 256) lit[i] = items[base + i];
  if (tid < BN) bin[tid] = 0;
  __syncthreads();
  for (int i = tid; i < cnt; i += 256) atomicAdd(&bin[(lit[i].x >> 16) & (BN - 1)], 1);
  __syncthreads();
  if (tid < BN) scn[tid] = bin[tid];
  __syncthreads();
  for (int d = 1; d < BN; d <<= 1) {
    int v = 0;
    if (tid < BN && tid >= d) v = scn[tid - d];
    __syncthreads();
    if (tid < BN) scn[tid] += v;
    __syncthreads();
  }
  if (tid < BN) {
    int incl = scn[tid];
    int excl = incl - bin[tid];
    cur[tid] = excl;
    int n = b * BN + tid;
    if (n < N) {
      nstart[n] = (int)base + excl;
      nend[n]   = (int)base + incl;
    }
  }
  __syncthreads();
  for (int i = tid; i < cnt; i += 256) {
    int2 it = lit[i];
    int pos = atomicAdd(&cur[(it.x >> 16) & (BN - 1)], 1);
    items[base + pos] = it;
  }
}

// ---------------------------------------------------------------------------
// Pull: one WAVE per node, register accumulator, no atomics.
// SGPR gather bases via readfirstlane; fp16 (base,delta) table -> 8B/lane.
__global__ __launch_bounds__(256)
void pull_kernel(const int* __restrict__ nstart, const int* __restrict__ nend,
                 const int2* __restrict__ items, const __half* __restrict__ rfh,
                 const uint2* __restrict__ Th, float* __restrict__ agg, int N) {
  const int wv = __builtin_amdgcn_readfirstlane(threadIdx.x >> 6);
  const int n = blockIdx.x * 4 + wv;
  if (n >= N) return;
  const int l = threadIdx.x & 63;
  int j  = nstart[n];
  const int j1 = nend[n];
  float a0 = 0.f, a1 = 0.f;

  for (; j + 4 <= j1; j += 4) {
    int2 p0 = items[j + 0];
    int2 p1 = items[j + 1];
    int2 p2 = items[j + 2];
    int2 p3 = items[j + 3];
    int sx0 = __builtin_amdgcn_readfirstlane(p0.x);
    int sy0 = __builtin_amdgcn_readfirstlane(p0.y);
    int sx1 = __builtin_amdgcn_readfirstlane(p1.x);
    int sy1 = __builtin_amdgcn_readfirstlane(p1.y);
    int sx2 = __builtin_amdgcn_readfirstlane(p2.x);
    int sy2 = __builtin_amdgcn_readfirstlane(p2.y);
    int sx3 = __builtin_amdgcn_readfirstlane(p3.x);
    int sy3 = __builtin_amdgcn_readfirstlane(p3.y);
    const uint2* tp0 = Th + ((size_t)(sy0 >> 16) << 6);
    const uint2* tp1 = Th + ((size_t)(sy1 >> 16) << 6);
    const uint2* tp2 = Th + ((size_t)(sy2 >> 16) << 6);
    const uint2* tp3 = Th + ((size_t)(sy3 >> 16) << 6);
    const __half* rp0 = rfh + ((size_t)(sx0 & 0xffff) << 7);
    const __half* rp1 = rfh + ((size_t)(sx1 & 0xffff) << 7);
    const __half* rp2 = rfh + ((size_t)(sx2 & 0xffff) << 7);
    const __half* rp3 = rfh + ((size_t)(sx3 & 0xffff) << 7);
    uint2 t0 = tp0[l];
    uint2 t1 = tp1[l];
    uint2 t2 = tp2[l];
    uint2 t3 = tp3[l];
    unsigned q0 = *(const unsigned*)(rp0 + 2 * l);
    unsigned q1 = *(const unsigned*)(rp1 + 2 * l);
    unsigned q2 = *(const unsigned*)(rp2 + 2 * l);
    unsigned q3 = *(const unsigned*)(rp3 + 2 * l);
    float f0 = __half2float(__ushort_as_half((unsigned short)sy0));
    float f1 = __half2float(__ushort_as_half((unsigned short)sy1));
    float f2 = __half2float(__ushort_as_half((unsigned short)sy2));
    float f3 = __half2float(__ushort_as_half((unsigned short)sy3));
    float2 r0 = __half22float2(*(const __half2*)&q0);
    float2 r1 = __half22float2(*(const __half2*)&q1);
    float2 r2 = __half22float2(*(const __half2*)&q2);
    float2 r3 = __half22float2(*(const __half2*)&q3);
    {
      float2 b0 = __half22float2(*(const __half2*)&t0.x);
      float2 c0 = __half22float2(*(const __half2*)&t0.y);
      a0 = __fmaf_rn(r0.x, __fmaf_rn(f0, b0.y, b0.x), a0);
      a1 = __fmaf_rn(r0.y, __fmaf_rn(f0, c0.y, c0.x), a1);
    }
    {
      float2 b1 = __half22float2(*(const __half2*)&t1.x);
      float2 c1 = __half22float2(*(const __half2*)&t1.y);
      a0 = __fmaf_rn(r1.x, __fmaf_rn(f1, b1.y, b1.x), a0);
      a1 = __fmaf_rn(r1.y, __fmaf_rn(f1, c1.y, c1.x), a1);
    }
    {
      float2 b2 = __half22float2(*(const __half2*)&t2.x);
      float2 c2 = __half22float2(*(const __half2*)&t2.y);
      a0 = __fmaf_rn(r2.x, __fmaf_rn(f2, b2.y, b2.x), a0);
      a1 = __fmaf_rn(r2.y, __fmaf_rn(f2, c2.y, c2.x), a1);
    }
    {
      float2 b3 = __half22float2(*(const __half2*)&t3.x);
      float2 c3 = __half22float2(*(const __half2*)&t3.y);
      a0 = __fmaf_rn(r3.x, __fmaf_rn(f3, b3.y, b3.x), a0);
      a1 = __fmaf_rn(r3.y, __fmaf_rn(f3, c3.y, c3.x), a1);
    }
  }
  for (; j < j1; ++j) {
    int2 p = items[j];
    int sx = __builtin_amdgcn_readfirstlane(p.x);
    int sy = __builtin_amdgcn_readfirstlane(p.y);
    const uint2* tp = Th + ((size_t)(sy >> 16) << 6);
    const __half* rp = rfh + ((size_t)(sx & 0xffff) << 7);
    uint2 tv = tp[l];
    unsigned qq = *(const unsigned*)(rp + 2 * l);
    float fr = __half2float(__ushort_as_half((unsigned short)sy));
    float2 rv = __half22float2(*(const __half2*)&qq);
    float2 bb = __half22float2(*(const __half2*)&tv.x);
    float2 cc = __half22float2(*(const __half2*)&tv.y);
    a0 = __fmaf_rn(rv.x, __fmaf_rn(fr, bb.y, bb.x), a0);
    a1 = __fmaf_rn(rv.y, __fmaf_rn(fr, cc.y, cc.x), a1);
  }
  float2 o; o.x = a0; o.y = a1;
  *(float2*)&agg[((size_t)n << 7) + 2 * l] = o;
}

// ---------------------------------------------------------------------------
extern "C" void kernel_launch(void* const* d_in, const int* in_sizes, int n_in,
                              void* d_out, int out_size, void* d_ws, size_t ws_size,
                              hipStream_t stream) {
  const float* r     = (const float*)d_in[0];
  const float* e     = (const float*)d_in[1];
  const int*   a     = (const int*)d_in[2];
  const float* W_df1 = (const float*)d_in[3];
  const float* b_df1 = (const float*)d_in[4];
  const float* W_df2 = (const float*)d_in[5];
  const float* b_df2 = (const float*)d_in[6];
  const float* W_af  = (const float*)d_in[7];
  const float* W_d1  = (const float*)d_in[8];
  const float* b_d1  = (const float*)d_in[9];
  const float* W_d2  = (const float*)d_in[10];
  const float* b_d2  = (const float*)d_in[11];

  const int N = in_sizes[0] / NAB;
  const int E = in_sizes[1];
  const int NB = (N + BN - 1) / BN;   // 1563 buckets

  // workspace layout (~70 MB). shared region: items [scatter->pull], then
  // t1 [gemm->gemm] — strictly sequential lifetimes.
  char* base = (char*)d_ws;
  size_t items_bytes = (size_t)NB * CAP * sizeof(int2);   // 30.4 MB
  size_t t1_bytes = (size_t)N * NAB * sizeof(float);      // 25.6 MB
  size_t shared_bytes = items_bytes > t1_bytes ? items_bytes : t1_bytes;
  int2*   items  = (int2*)base;                           // first life
  float*  t1     = (float*)base;                          // second life
  float*  agg    = (float*)(base + shared_bytes);         // N*128 fp32
  __half* rfh    = (__half*)(agg + (size_t)N * NAB);      // N*128 fp16
  uint2*  Th     = (uint2*)(rfh + (size_t)N * NAB);       // (TK-1)*64*8B
  int*    bcur   = (int*)(Th + (size_t)(TK - 1) * 64);    // NB*CPAD
  int*    nstart = bcur + NB * CPAD;                      // N
  int*    nend   = nstart + N;                            // N

  const int gblocks = (N + 31) / 32;

  // 1) fp16 (base,delta) ef lerp table
  build_tp<<<TK - 1, 128, 0, stream>>>(W_df1, b_df1, W_df2, b_df2, Th);
  // 2) rfh = fp16(r @ W_af) — fused cast epilogue
  gemm128<<<gblocks, 128, 0, stream>>>(r, W_af, nullptr, rfh, N, 2);
  // 3) both-direction slot-scatter into 32-node buckets (1 thread per edge)
  hipMemsetAsync(bcur, 0, (size_t)NB * CPAD * sizeof(int), stream);
  bscatter_kernel<<<(E + 255) / 256, 256, 0, stream>>>((const int2*)a, e, bcur, items, E);
  // 4) per-bucket counting sort -> node-ordered items + CSR
  local_sort<<<NB, 256, 0, stream>>>(bcur, items, nstart, nend, N);
  // 5) wave-per-node pull (SGPR gather bases, fp16 rf, fp16 base/delta table)
  pull_kernel<<<(N + 3) / 4, 256, 0, stream>>>(nstart, nend, items, rfh, Th, agg, N);
  // 6) t1 = ssp(agg @ W_d1 + b_d1)
  gemm128<<<gblocks, 128, 0, stream>>>(agg, W_d1, b_d1, t1, N, 1);
  // 7) out = t1 @ W_d2 + b_d2
  gemm128<<<gblocks, 128, 0, stream>>>(t1, W_d2, b_d2, d_out, N, 0);
}

// Round 5
// 504.174 us; speedup vs baseline: 1.4328x; 1.2186x over previous
//
#include <hip/hip_runtime.h>
#include <hip/hip_fp16.h>
#include <math.h>

#define NAB 128
#define NG 50
#define TK 1024      // ef interpolation grid points
#define BN 128       // nodes per bucket
#define NSTRIPE 8    // sub-buckets per bucket, one per XCD (bid & 7)
#define CAPS 1216    // slots per (bucket, stripe): mean 1024, +6 sigma
#define BSTRIDE (NSTRIPE * CAPS)   // 9728 slots per bucket region
#define CAPB 8704    // LDS staging capacity per bucket (verified bucket max)
#define CPAD 16      // ints per cursor (own 64B line)

__device__ __forceinline__ float sspf(float x) {
  float t = __expf(-fabsf(x));
  return fmaxf(x, 0.0f) + __logf(1.0f + t) - 0.69314718055994531f;
}

// ---------------------------------------------------------------------------
// C[M,128] = A[M,128] @ W[128,128] (+ bias).
// mode: 0 = fp32 store, 1 = fp32 + ssp store, 2 = fp16 store (fused rf cast)
__global__ __launch_bounds__(128)
void gemm128(const float* __restrict__ A, const float* __restrict__ W,
             const float* __restrict__ bias, void* __restrict__ Cout,
             int M, int mode) {
  __shared__ float Al[32 * 128];
  const int tid = threadIdx.x;
  const int r0 = blockIdx.x * 32;
  const int rows = min(32, M - r0);

  {
    const float4* A4 = (const float4*)(A + (size_t)r0 * NAB);
    float4* Al4 = (float4*)Al;
    for (int f = tid; f < rows * 32; f += 128) Al4[f] = A4[f];
  }
  __syncthreads();

  const int c = tid & 31;
  const int gq = tid >> 5;
  float acc[8][4];
#pragma unroll
  for (int j = 0; j < 8; ++j) {
    acc[j][0] = 0.f; acc[j][1] = 0.f; acc[j][2] = 0.f; acc[j][3] = 0.f;
  }
  const float4* W4 = (const float4*)W;
  for (int i = 0; i < 128; i += 4) {
    float4 w0 = W4[(i + 0) * 32 + c];
    float4 w1 = W4[(i + 1) * 32 + c];
    float4 w2 = W4[(i + 2) * 32 + c];
    float4 w3 = W4[(i + 3) * 32 + c];
#pragma unroll
    for (int j = 0; j < 8; ++j) {
      float4 av = *(const float4*)&Al[(gq * 8 + j) * 128 + i];
      acc[j][0] += av.x * w0.x + av.y * w1.x + av.z * w2.x + av.w * w3.x;
      acc[j][1] += av.x * w0.y + av.y * w1.y + av.z * w2.y + av.w * w3.y;
      acc[j][2] += av.x * w0.z + av.y * w1.z + av.z * w2.z + av.w * w3.z;
      acc[j][3] += av.x * w0.w + av.y * w1.w + av.z * w2.w + av.w * w3.w;
    }
  }
  float4 bv = make_float4(0.f, 0.f, 0.f, 0.f);
  if (bias) bv = *(const float4*)&bias[4 * c];
#pragma unroll
  for (int j = 0; j < 8; ++j) {
    int row = gq * 8 + j;
    if (row < rows) {
      float4 o;
      o.x = acc[j][0] + bv.x;
      o.y = acc[j][1] + bv.y;
      o.z = acc[j][2] + bv.z;
      o.w = acc[j][3] + bv.w;
      if (mode == 1) { o.x = sspf(o.x); o.y = sspf(o.y); o.z = sspf(o.z); o.w = sspf(o.w); }
      if (mode == 2) {
        __half2 h01 = __floats2half2_rn(o.x, o.y);
        __half2 h23 = __floats2half2_rn(o.z, o.w);
        uint2 u;
        u.x = *(unsigned*)&h01;
        u.y = *(unsigned*)&h23;
        *(uint2*)((__half*)Cout + (size_t)(r0 + row) * NAB + 4 * c) = u;
      } else {
        *(float4*)((float*)Cout + (size_t)(r0 + row) * NAB + 4 * c) = o;
      }
    }
  }
}

// ---------------------------------------------------------------------------
// Build fp16 (base, delta) lerp table (unchanged from R2).
__global__ __launch_bounds__(128)
void build_tp(const float* __restrict__ W1, const float* __restrict__ b1,
              const float* __restrict__ W2, const float* __restrict__ b2,
              uint2* __restrict__ Th) {
  __shared__ float h0[NG], h1[NG], e0[NAB], e1[NAB];
  const int k = blockIdx.x;       // 0 .. TK-2
  const int tid = threadIdx.x;
  constexpr float width = 5.0f / 49.0f;
  constexpr float coeff = -0.5f / (width * width);
  const float x0 = (float)k * (5.0f / (float)(TK - 1));
  const float x1 = (float)(k + 1) * (5.0f / (float)(TK - 1));

  if (tid < NG) {
    float a0 = b1[tid], a1 = b1[tid];
    for (int i = 0; i < NG; ++i) {
      float w = W1[i * NG + tid];
      float d0 = x0 - i * width;
      float d1 = x1 - i * width;
      a0 = __fmaf_rn(__expf(coeff * d0 * d0), w, a0);
      a1 = __fmaf_rn(__expf(coeff * d1 * d1), w, a1);
    }
    h0[tid] = sspf(a0);
    h1[tid] = sspf(a1);
  }
  __syncthreads();
  float f0 = b2[tid], f1 = b2[tid];
#pragma unroll 10
  for (int i = 0; i < NG; ++i) {
    float w = W2[i * NAB + tid];
    f0 = __fmaf_rn(h0[i], w, f0);
    f1 = __fmaf_rn(h1[i], w, f1);
  }
  e0[tid] = f0;
  e1[tid] = f1;
  __syncthreads();
  if (tid < 64) {
    float b0 = e0[2 * tid],      d0 = e1[2 * tid]     - e0[2 * tid];
    float b1v = e0[2 * tid + 1], d1 = e1[2 * tid + 1] - e0[2 * tid + 1];
    __half2 p0 = __floats2half2_rn(b0, d0);
    __half2 p1 = __floats2half2_rn(b1v, d1);
    uint2 u;
    u.x = *(unsigned*)&p0;
    u.y = *(unsigned*)&p1;
    Th[(size_t)k * 64 + tid] = u;
  }
}

// ---------------------------------------------------------------------------
// Scatter (src | tl<<16, k<<16 | half(f)) into per-(bucket, stripe) slots.
// stripe = blockIdx & 7 ~ XCD id (round-robin dispatch): every sub-array is
// appended by ONE XCD's L2 -> 64B lines fill completely -> ~1x write amp.
__global__ __launch_bounds__(256)
void bscatter_kernel(const int* __restrict__ a, const float* __restrict__ e,
                     int* __restrict__ bcur, int2* __restrict__ items, int E) {
  int i = blockIdx.x * 256 + threadIdx.x;
  if (i >= 2 * E) return;
  const int s = blockIdx.x & (NSTRIPE - 1);
  int edge, tgt, src;
  if (i < E) {
    edge = i; src = a[2 * i]; tgt = a[2 * i + 1];
  } else {
    edge = i - E; tgt = a[2 * edge]; src = a[2 * edge + 1];
  }
  const float scale = (float)(TK - 1) / 5.0f;
  float x = e[edge] * scale;
  int k = min((int)x, TK - 2);
  float f = x - (float)k;
  int payload = (k << 16) | (int)__half_as_ushort(__float2half_rn(f));
  int b = tgt >> 7;
  int cell = b * NSTRIPE + s;
  int pos = atomicAdd(&bcur[cell * CPAD], 1);
  if (pos < CAPS)
    items[(size_t)cell * CAPS + pos] = make_int2(src | ((tgt & 127) << 16), payload);
}

// ---------------------------------------------------------------------------
// Per-bucket counting sort: concatenate the 8 stripe segments in LDS, then
// node counting sort -> node-ordered items + CSR (same as R2 downstream).
__global__ __launch_bounds__(256)
void local_sort(const int* __restrict__ bcur, int2* __restrict__ items,
                int* __restrict__ nstart, int* __restrict__ nend, int N) {
  __shared__ int2 lit[CAPB];
  __shared__ int bin[BN], cur[BN], scn[BN];
  __shared__ int sofs[NSTRIPE + 1];
  const int b = blockIdx.x;
  const int tid = threadIdx.x;
  const size_t base = (size_t)b * BSTRIDE;

  if (tid == 0) {
    int t = 0;
    for (int s = 0; s < NSTRIPE; ++s) {
      sofs[s] = t;
      int c = min(bcur[(b * NSTRIPE + s) * CPAD], CAPS);
      t += c;
      if (t > CAPB) t = CAPB;
    }
    sofs[NSTRIPE] = t;
  }
  __syncthreads();
  const int cnt = sofs[NSTRIPE];
  for (int s = 0; s < NSTRIPE; ++s) {
    const int o = sofs[s];
    const int c = sofs[s + 1] - o;
    const int2* srcp = items + base + (size_t)s * CAPS;
    for (int i = tid; i < c; i += 256) lit[o + i] = srcp[i];
  }
  if (tid < BN) bin[tid] = 0;
  __syncthreads();
  for (int i = tid; i < cnt; i += 256) atomicAdd(&bin[(lit[i].x >> 16) & (BN - 1)], 1);
  __syncthreads();
  if (tid < BN) scn[tid] = bin[tid];
  __syncthreads();
  for (int d = 1; d < BN; d <<= 1) {
    int v = 0;
    if (tid < BN && tid >= d) v = scn[tid - d];
    __syncthreads();
    if (tid < BN) scn[tid] += v;
    __syncthreads();
  }
  if (tid < BN) {
    int incl = scn[tid];
    int excl = incl - bin[tid];
    cur[tid] = excl;
    int n = b * BN + tid;
    if (n < N) {
      nstart[n] = (int)base + excl;
      nend[n]   = (int)base + incl;
    }
  }
  __syncthreads();
  for (int i = tid; i < cnt; i += 256) {
    int2 it = lit[i];
    int pos = atomicAdd(&cur[(it.x >> 16) & (BN - 1)], 1);
    items[base + pos] = it;
  }
}

// ---------------------------------------------------------------------------
// Pull: one WAVE per node, register accumulator, no atomics.
// SGPR gather bases via readfirstlane; fp16 (base,delta) table -> 8B/lane.
__global__ __launch_bounds__(256)
void pull_kernel(const int* __restrict__ nstart, const int* __restrict__ nend,
                 const int2* __restrict__ items, const __half* __restrict__ rfh,
                 const uint2* __restrict__ Th, float* __restrict__ agg, int N) {
  const int wv = __builtin_amdgcn_readfirstlane(threadIdx.x >> 6);
  const int n = blockIdx.x * 4 + wv;
  if (n >= N) return;
  const int l = threadIdx.x & 63;
  int j  = nstart[n];
  const int j1 = nend[n];
  float a0 = 0.f, a1 = 0.f;

  for (; j + 4 <= j1; j += 4) {
    int2 p0 = items[j + 0];
    int2 p1 = items[j + 1];
    int2 p2 = items[j + 2];
    int2 p3 = items[j + 3];
    int sx0 = __builtin_amdgcn_readfirstlane(p0.x);
    int sy0 = __builtin_amdgcn_readfirstlane(p0.y);
    int sx1 = __builtin_amdgcn_readfirstlane(p1.x);
    int sy1 = __builtin_amdgcn_readfirstlane(p1.y);
    int sx2 = __builtin_amdgcn_readfirstlane(p2.x);
    int sy2 = __builtin_amdgcn_readfirstlane(p2.y);
    int sx3 = __builtin_amdgcn_readfirstlane(p3.x);
    int sy3 = __builtin_amdgcn_readfirstlane(p3.y);
    const uint2* tp0 = Th + ((size_t)(sy0 >> 16) << 6);
    const uint2* tp1 = Th + ((size_t)(sy1 >> 16) << 6);
    const uint2* tp2 = Th + ((size_t)(sy2 >> 16) << 6);
    const uint2* tp3 = Th + ((size_t)(sy3 >> 16) << 6);
    const __half* rp0 = rfh + ((size_t)(sx0 & 0xffff) << 7);
    const __half* rp1 = rfh + ((size_t)(sx1 & 0xffff) << 7);
    const __half* rp2 = rfh + ((size_t)(sx2 & 0xffff) << 7);
    const __half* rp3 = rfh + ((size_t)(sx3 & 0xffff) << 7);
    uint2 t0 = tp0[l];
    uint2 t1 = tp1[l];
    uint2 t2 = tp2[l];
    uint2 t3 = tp3[l];
    unsigned q0 = *(const unsigned*)(rp0 + 2 * l);
    unsigned q1 = *(const unsigned*)(rp1 + 2 * l);
    unsigned q2 = *(const unsigned*)(rp2 + 2 * l);
    unsigned q3 = *(const unsigned*)(rp3 + 2 * l);
    float f0 = __half2float(__ushort_as_half((unsigned short)sy0));
    float f1 = __half2float(__ushort_as_half((unsigned short)sy1));
    float f2 = __half2float(__ushort_as_half((unsigned short)sy2));
    float f3 = __half2float(__ushort_as_half((unsigned short)sy3));
    float2 r0 = __half22float2(*(const __half2*)&q0);
    float2 r1 = __half22float2(*(const __half2*)&q1);
    float2 r2 = __half22float2(*(const __half2*)&q2);
    float2 r3 = __half22float2(*(const __half2*)&q3);
    {
      float2 b0 = __half22float2(*(const __half2*)&t0.x);
      float2 c0 = __half22float2(*(const __half2*)&t0.y);
      a0 = __fmaf_rn(r0.x, __fmaf_rn(f0, b0.y, b0.x), a0);
      a1 = __fmaf_rn(r0.y, __fmaf_rn(f0, c0.y, c0.x), a1);
    }
    {
      float2 b1 = __half22float2(*(const __half2*)&t1.x);
      float2 c1 = __half22float2(*(const __half2*)&t1.y);
      a0 = __fmaf_rn(r1.x, __fmaf_rn(f1, b1.y, b1.x), a0);
      a1 = __fmaf_rn(r1.y, __fmaf_rn(f1, c1.y, c1.x), a1);
    }
    {
      float2 b2 = __half22float2(*(const __half2*)&t2.x);
      float2 c2 = __half22float2(*(const __half2*)&t2.y);
      a0 = __fmaf_rn(r2.x, __fmaf_rn(f2, b2.y, b2.x), a0);
      a1 = __fmaf_rn(r2.y, __fmaf_rn(f2, c2.y, c2.x), a1);
    }
    {
      float2 b3 = __half22float2(*(const __half2*)&t3.x);
      float2 c3 = __half22float2(*(const __half2*)&t3.y);
      a0 = __fmaf_rn(r3.x, __fmaf_rn(f3, b3.y, b3.x), a0);
      a1 = __fmaf_rn(r3.y, __fmaf_rn(f3, c3.y, c3.x), a1);
    }
  }
  for (; j < j1; ++j) {
    int2 p = items[j];
    int sx = __builtin_amdgcn_readfirstlane(p.x);
    int sy = __builtin_amdgcn_readfirstlane(p.y);
    const uint2* tp = Th + ((size_t)(sy >> 16) << 6);
    const __half* rp = rfh + ((size_t)(sx & 0xffff) << 7);
    uint2 tv = tp[l];
    unsigned qq = *(const unsigned*)(rp + 2 * l);
    float fr = __half2float(__ushort_as_half((unsigned short)sy));
    float2 rv = __half22float2(*(const __half2*)&qq);
    float2 bb = __half22float2(*(const __half2*)&tv.x);
    float2 cc = __half22float2(*(const __half2*)&tv.y);
    a0 = __fmaf_rn(rv.x, __fmaf_rn(fr, bb.y, bb.x), a0);
    a1 = __fmaf_rn(rv.y, __fmaf_rn(fr, cc.y, cc.x), a1);
  }
  float2 o; o.x = a0; o.y = a1;
  *(float2*)&agg[((size_t)n << 7) + 2 * l] = o;
}

// ---------------------------------------------------------------------------
extern "C" void kernel_launch(void* const* d_in, const int* in_sizes, int n_in,
                              void* d_out, int out_size, void* d_ws, size_t ws_size,
                              hipStream_t stream) {
  const float* r     = (const float*)d_in[0];
  const float* e     = (const float*)d_in[1];
  const int*   a     = (const int*)d_in[2];
  const float* W_df1 = (const float*)d_in[3];
  const float* b_df1 = (const float*)d_in[4];
  const float* W_df2 = (const float*)d_in[5];
  const float* b_df2 = (const float*)d_in[6];
  const float* W_af  = (const float*)d_in[7];
  const float* W_d1  = (const float*)d_in[8];
  const float* b_d1  = (const float*)d_in[9];
  const float* W_d2  = (const float*)d_in[10];
  const float* b_d2  = (const float*)d_in[11];

  const int N = in_sizes[0] / NAB;
  const int E = in_sizes[1];
  const int H = 2 * E;
  const int NB = (N + BN - 1) / BN;   // 391 buckets

  // workspace layout (~70 MB). shared region: items [scatter->pull], then
  // t1 [gemm->gemm] — strictly sequential lifetimes.
  char* base = (char*)d_ws;
  size_t items_bytes = (size_t)NB * BSTRIDE * sizeof(int2);   // 30.4 MB
  size_t t1_bytes = (size_t)N * NAB * sizeof(float);          // 25.6 MB
  size_t shared_bytes = items_bytes > t1_bytes ? items_bytes : t1_bytes;
  int2*   items  = (int2*)base;                           // first life
  float*  t1     = (float*)base;                          // second life
  float*  agg    = (float*)(base + shared_bytes);         // N*128 fp32
  __half* rfh    = (__half*)(agg + (size_t)N * NAB);      // N*128 fp16
  uint2*  Th     = (uint2*)(rfh + (size_t)N * NAB);       // (TK-1)*64*8B
  int*    bcur   = (int*)(Th + (size_t)(TK - 1) * 64);    // NB*NSTRIPE*CPAD
  int*    nstart = bcur + NB * NSTRIPE * CPAD;            // N
  int*    nend   = nstart + N;                            // N

  const int gblocks = (N + 31) / 32;
  const int hblocks = (H + 255) / 256;

  // 1) fp16 (base,delta) ef lerp table
  build_tp<<<TK - 1, 128, 0, stream>>>(W_df1, b_df1, W_df2, b_df2, Th);
  // 2) rfh = fp16(r @ W_af) — fused cast epilogue
  gemm128<<<gblocks, 128, 0, stream>>>(r, W_af, nullptr, rfh, N, 2);
  // 3) XCD-striped slot-scatter into 128-node buckets
  hipMemsetAsync(bcur, 0, (size_t)NB * NSTRIPE * CPAD * sizeof(int), stream);
  bscatter_kernel<<<hblocks, 256, 0, stream>>>(a, e, bcur, items, E);
  // 4) per-bucket stripe-concat + counting sort -> node-ordered items + CSR
  local_sort<<<NB, 256, 0, stream>>>(bcur, items, nstart, nend, N);
  // 5) wave-per-node pull (SGPR gather bases, fp16 rf, fp16 base/delta table)
  pull_kernel<<<(N + 3) / 4, 256, 0, stream>>>(nstart, nend, items, rfh, Th, agg, N);
  // 6) t1 = ssp(agg @ W_d1 + b_d1)
  gemm128<<<gblocks, 128, 0, stream>>>(agg, W_d1, b_d1, t1, N, 1);
  // 7) out = t1 @ W_d2 + b_d2
  gemm128<<<gblocks, 128, 0, stream>>>(t1, W_d2, b_d2, d_out, N, 0);
}

// Round 6
// 404.462 us; speedup vs baseline: 1.7860x; 1.2465x over previous
//
#include <hip/hip_runtime.h>
#include <hip/hip_fp16.h>
#include <math.h>

#define NAB 128
#define NG 50
#define TK 1024      // ef interpolation grid points
#define BN 128       // nodes per bucket
#define CAPB 8704    // LDS staging capacity per bucket (verified bucket max)
#define NBLK 256     // radix partition blocks (chunks)
#define TPB 1024     // threads per radix block
#define NBMAX 400    // LDS bins (>= NB=391)

__device__ __forceinline__ float sspf(float x) {
  float t = __expf(-fabsf(x));
  return fmaxf(x, 0.0f) + __logf(1.0f + t) - 0.69314718055994531f;
}

// ---------------------------------------------------------------------------
// C[M,128] = A[M,128] @ W[128,128] (+ bias).
// mode: 0 = fp32 store, 1 = fp32 + ssp store, 2 = fp16 store (fused rf cast)
__global__ __launch_bounds__(128)
void gemm128(const float* __restrict__ A, const float* __restrict__ W,
             const float* __restrict__ bias, void* __restrict__ Cout,
             int M, int mode) {
  __shared__ float Al[32 * 128];
  const int tid = threadIdx.x;
  const int r0 = blockIdx.x * 32;
  const int rows = min(32, M - r0);

  {
    const float4* A4 = (const float4*)(A + (size_t)r0 * NAB);
    float4* Al4 = (float4*)Al;
    for (int f = tid; f < rows * 32; f += 128) Al4[f] = A4[f];
  }
  __syncthreads();

  const int c = tid & 31;
  const int gq = tid >> 5;
  float acc[8][4];
#pragma unroll
  for (int j = 0; j < 8; ++j) {
    acc[j][0] = 0.f; acc[j][1] = 0.f; acc[j][2] = 0.f; acc[j][3] = 0.f;
  }
  const float4* W4 = (const float4*)W;
  for (int i = 0; i < 128; i += 4) {
    float4 w0 = W4[(i + 0) * 32 + c];
    float4 w1 = W4[(i + 1) * 32 + c];
    float4 w2 = W4[(i + 2) * 32 + c];
    float4 w3 = W4[(i + 3) * 32 + c];
#pragma unroll
    for (int j = 0; j < 8; ++j) {
      float4 av = *(const float4*)&Al[(gq * 8 + j) * 128 + i];
      acc[j][0] += av.x * w0.x + av.y * w1.x + av.z * w2.x + av.w * w3.x;
      acc[j][1] += av.x * w0.y + av.y * w1.y + av.z * w2.y + av.w * w3.y;
      acc[j][2] += av.x * w0.z + av.y * w1.z + av.z * w2.z + av.w * w3.z;
      acc[j][3] += av.x * w0.w + av.y * w1.w + av.z * w2.w + av.w * w3.w;
    }
  }
  float4 bv = make_float4(0.f, 0.f, 0.f, 0.f);
  if (bias) bv = *(const float4*)&bias[4 * c];
#pragma unroll
  for (int j = 0; j < 8; ++j) {
    int row = gq * 8 + j;
    if (row < rows) {
      float4 o;
      o.x = acc[j][0] + bv.x;
      o.y = acc[j][1] + bv.y;
      o.z = acc[j][2] + bv.z;
      o.w = acc[j][3] + bv.w;
      if (mode == 1) { o.x = sspf(o.x); o.y = sspf(o.y); o.z = sspf(o.z); o.w = sspf(o.w); }
      if (mode == 2) {
        __half2 h01 = __floats2half2_rn(o.x, o.y);
        __half2 h23 = __floats2half2_rn(o.z, o.w);
        uint2 u;
        u.x = *(unsigned*)&h01;
        u.y = *(unsigned*)&h23;
        *(uint2*)((__half*)Cout + (size_t)(r0 + row) * NAB + 4 * c) = u;
      } else {
        *(float4*)((float*)Cout + (size_t)(r0 + row) * NAB + 4 * c) = o;
      }
    }
  }
}

// ---------------------------------------------------------------------------
// Build fp16 (base, delta) lerp table (unchanged from R2).
__global__ __launch_bounds__(128)
void build_tp(const float* __restrict__ W1, const float* __restrict__ b1,
              const float* __restrict__ W2, const float* __restrict__ b2,
              uint2* __restrict__ Th) {
  __shared__ float h0[NG], h1[NG], e0[NAB], e1[NAB];
  const int k = blockIdx.x;       // 0 .. TK-2
  const int tid = threadIdx.x;
  constexpr float width = 5.0f / 49.0f;
  constexpr float coeff = -0.5f / (width * width);
  const float x0 = (float)k * (5.0f / (float)(TK - 1));
  const float x1 = (float)(k + 1) * (5.0f / (float)(TK - 1));

  if (tid < NG) {
    float a0 = b1[tid], a1 = b1[tid];
    for (int i = 0; i < NG; ++i) {
      float w = W1[i * NG + tid];
      float d0 = x0 - i * width;
      float d1 = x1 - i * width;
      a0 = __fmaf_rn(__expf(coeff * d0 * d0), w, a0);
      a1 = __fmaf_rn(__expf(coeff * d1 * d1), w, a1);
    }
    h0[tid] = sspf(a0);
    h1[tid] = sspf(a1);
  }
  __syncthreads();
  float f0 = b2[tid], f1 = b2[tid];
#pragma unroll 10
  for (int i = 0; i < NG; ++i) {
    float w = W2[i * NAB + tid];
    f0 = __fmaf_rn(h0[i], w, f0);
    f1 = __fmaf_rn(h1[i], w, f1);
  }
  e0[tid] = f0;
  e1[tid] = f1;
  __syncthreads();
  if (tid < 64) {
    float b0 = e0[2 * tid],      d0 = e1[2 * tid]     - e0[2 * tid];
    float b1v = e0[2 * tid + 1], d1 = e1[2 * tid + 1] - e0[2 * tid + 1];
    __half2 p0 = __floats2half2_rn(b0, d0);
    __half2 p1 = __floats2half2_rn(b1v, d1);
    uint2 u;
    u.x = *(unsigned*)&p0;
    u.y = *(unsigned*)&p1;
    Th[(size_t)k * 64 + tid] = u;
  }
}

// ---------------------------------------------------------------------------
// Radix P1: per-block LDS histogram of bucket ids (both edge directions).
// hist is bucket-major: hist[bucket * NBLK + block].
__global__ __launch_bounds__(TPB)
void hist_pass(const int2* __restrict__ a2, int* __restrict__ hist,
               int E, int NB) {
  __shared__ int h[NBMAX];
  const int blk = blockIdx.x;
  const int chunk = (E + NBLK - 1) / NBLK;
  const int lo = blk * chunk;
  const int hi = min(E, lo + chunk);
  for (int i = threadIdx.x; i < NB; i += TPB) h[i] = 0;
  __syncthreads();
  for (int i = lo + threadIdx.x; i < hi; i += TPB) {
    int2 p = a2[i];
    atomicAdd(&h[p.y >> 7], 1);
    atomicAdd(&h[p.x >> 7], 1);
  }
  __syncthreads();
  for (int i = threadIdx.x; i < NB; i += TPB) hist[i * NBLK + blk] = h[i];
}

// ---------------------------------------------------------------------------
// Scan A: one block per bucket; exclusive scan of its NBLK counts in-place,
// bucket total -> btot.
__global__ __launch_bounds__(NBLK)
void scan_bucket(int* __restrict__ hist, int* __restrict__ btot) {
  __shared__ int s[NBLK];
  const int b = blockIdx.x;
  const int t = threadIdx.x;
  int v = hist[b * NBLK + t];
  s[t] = v;
  __syncthreads();
  for (int d = 1; d < NBLK; d <<= 1) {
    int u = (t >= d) ? s[t - d] : 0;
    __syncthreads();
    s[t] += u;
    __syncthreads();
  }
  hist[b * NBLK + t] = s[t] - v;            // exclusive within bucket
  if (t == NBLK - 1) btot[b] = s[t];
}

// ---------------------------------------------------------------------------
// Scan B: exclusive scan of bucket totals (NB <= 512), single block.
__global__ __launch_bounds__(512)
void scan_bbase(const int* __restrict__ btot, int* __restrict__ bbase, int NB) {
  __shared__ int s[512];
  int t = threadIdx.x;
  int v = (t < NB) ? btot[t] : 0;
  s[t] = v;
  __syncthreads();
  for (int d = 1; d < 512; d <<= 1) {
    int u = (t >= d) ? s[t - d] : 0;
    __syncthreads();
    s[t] += u;
    __syncthreads();
  }
  if (t < NB) bbase[t] = s[t] - v;
}

// ---------------------------------------------------------------------------
// Radix P2: re-read chunk, payload once per edge, append via LDS cursors into
// pre-reserved disjoint ranges. Zero global atomics; bucket-contiguous output.
__global__ __launch_bounds__(TPB)
void scatter_pass(const int2* __restrict__ a2, const float* __restrict__ e,
                  const int* __restrict__ hist, const int* __restrict__ bbase,
                  int2* __restrict__ items, int E, int NB) {
  __shared__ int cur[NBMAX];
  const int blk = blockIdx.x;
  const int chunk = (E + NBLK - 1) / NBLK;
  const int lo = blk * chunk;
  const int hi = min(E, lo + chunk);
  for (int i = threadIdx.x; i < NB; i += TPB)
    cur[i] = bbase[i] + hist[i * NBLK + blk];
  __syncthreads();
  const float scale = (float)(TK - 1) / 5.0f;
  for (int i = lo + threadIdx.x; i < hi; i += TPB) {
    int2 p = a2[i];
    float x = e[i] * scale;
    int k = min((int)x, TK - 2);
    float f = x - (float)k;
    int payload = (k << 16) | (int)__half_as_ushort(__float2half_rn(f));
    int pos0 = atomicAdd(&cur[p.y >> 7], 1);
    items[pos0] = make_int2(p.x | ((p.y & 127) << 16), payload);
    int pos1 = atomicAdd(&cur[p.x >> 7], 1);
    items[pos1] = make_int2(p.y | ((p.x & 127) << 16), payload);
  }
}

// ---------------------------------------------------------------------------
// Per-bucket counting sort (dense layout: bucket b at [bbase[b], +btot[b])).
__global__ __launch_bounds__(256)
void local_sort(const int* __restrict__ bbase, const int* __restrict__ btot,
                int2* __restrict__ items,
                int* __restrict__ nstart, int* __restrict__ nend, int N) {
  __shared__ int2 lit[CAPB];
  __shared__ int bin[BN], cur[BN], scn[BN];
  const int b = blockIdx.x;
  const int tid = threadIdx.x;
  const int cnt = min(btot[b], CAPB);
  const int base = bbase[b];

  for (int i = tid; i < cnt; i += 256) lit[i] = items[base + i];
  if (tid < BN) bin[tid] = 0;
  __syncthreads();
  for (int i = tid; i < cnt; i += 256) atomicAdd(&bin[(lit[i].x >> 16) & (BN - 1)], 1);
  __syncthreads();
  if (tid < BN) scn[tid] = bin[tid];
  __syncthreads();
  for (int d = 1; d < BN; d <<= 1) {
    int v = 0;
    if (tid < BN && tid >= d) v = scn[tid - d];
    __syncthreads();
    if (tid < BN) scn[tid] += v;
    __syncthreads();
  }
  if (tid < BN) {
    int incl = scn[tid];
    int excl = incl - bin[tid];
    cur[tid] = excl;
    int n = b * BN + tid;
    if (n < N) {
      nstart[n] = base + excl;
      nend[n]   = base + incl;
    }
  }
  __syncthreads();
  for (int i = tid; i < cnt; i += 256) {
    int2 it = lit[i];
    int pos = atomicAdd(&cur[(it.x >> 16) & (BN - 1)], 1);
    items[base + pos] = it;
  }
}

// ---------------------------------------------------------------------------
// Pull: one WAVE per node, register accumulator, no atomics.
// SGPR gather bases via readfirstlane; fp16 (base,delta) table -> 8B/lane.
__global__ __launch_bounds__(256)
void pull_kernel(const int* __restrict__ nstart, const int* __restrict__ nend,
                 const int2* __restrict__ items, const __half* __restrict__ rfh,
                 const uint2* __restrict__ Th, float* __restrict__ agg, int N) {
  const int wv = __builtin_amdgcn_readfirstlane(threadIdx.x >> 6);
  const int n = blockIdx.x * 4 + wv;
  if (n >= N) return;
  const int l = threadIdx.x & 63;
  int j  = nstart[n];
  const int j1 = nend[n];
  float a0 = 0.f, a1 = 0.f;

  for (; j + 4 <= j1; j += 4) {
    int2 p0 = items[j + 0];
    int2 p1 = items[j + 1];
    int2 p2 = items[j + 2];
    int2 p3 = items[j + 3];
    int sx0 = __builtin_amdgcn_readfirstlane(p0.x);
    int sy0 = __builtin_amdgcn_readfirstlane(p0.y);
    int sx1 = __builtin_amdgcn_readfirstlane(p1.x);
    int sy1 = __builtin_amdgcn_readfirstlane(p1.y);
    int sx2 = __builtin_amdgcn_readfirstlane(p2.x);
    int sy2 = __builtin_amdgcn_readfirstlane(p2.y);
    int sx3 = __builtin_amdgcn_readfirstlane(p3.x);
    int sy3 = __builtin_amdgcn_readfirstlane(p3.y);
    const uint2* tp0 = Th + ((size_t)(sy0 >> 16) << 6);
    const uint2* tp1 = Th + ((size_t)(sy1 >> 16) << 6);
    const uint2* tp2 = Th + ((size_t)(sy2 >> 16) << 6);
    const uint2* tp3 = Th + ((size_t)(sy3 >> 16) << 6);
    const __half* rp0 = rfh + ((size_t)(sx0 & 0xffff) << 7);
    const __half* rp1 = rfh + ((size_t)(sx1 & 0xffff) << 7);
    const __half* rp2 = rfh + ((size_t)(sx2 & 0xffff) << 7);
    const __half* rp3 = rfh + ((size_t)(sx3 & 0xffff) << 7);
    uint2 t0 = tp0[l];
    uint2 t1 = tp1[l];
    uint2 t2 = tp2[l];
    uint2 t3 = tp3[l];
    unsigned q0 = *(const unsigned*)(rp0 + 2 * l);
    unsigned q1 = *(const unsigned*)(rp1 + 2 * l);
    unsigned q2 = *(const unsigned*)(rp2 + 2 * l);
    unsigned q3 = *(const unsigned*)(rp3 + 2 * l);
    float f0 = __half2float(__ushort_as_half((unsigned short)sy0));
    float f1 = __half2float(__ushort_as_half((unsigned short)sy1));
    float f2 = __half2float(__ushort_as_half((unsigned short)sy2));
    float f3 = __half2float(__ushort_as_half((unsigned short)sy3));
    float2 r0 = __half22float2(*(const __half2*)&q0);
    float2 r1 = __half22float2(*(const __half2*)&q1);
    float2 r2 = __half22float2(*(const __half2*)&q2);
    float2 r3 = __half22float2(*(const __half2*)&q3);
    {
      float2 b0 = __half22float2(*(const __half2*)&t0.x);
      float2 c0 = __half22float2(*(const __half2*)&t0.y);
      a0 = __fmaf_rn(r0.x, __fmaf_rn(f0, b0.y, b0.x), a0);
      a1 = __fmaf_rn(r0.y, __fmaf_rn(f0, c0.y, c0.x), a1);
    }
    {
      float2 b1 = __half22float2(*(const __half2*)&t1.x);
      float2 c1 = __half22float2(*(const __half2*)&t1.y);
      a0 = __fmaf_rn(r1.x, __fmaf_rn(f1, b1.y, b1.x), a0);
      a1 = __fmaf_rn(r1.y, __fmaf_rn(f1, c1.y, c1.x), a1);
    }
    {
      float2 b2 = __half22float2(*(const __half2*)&t2.x);
      float2 c2 = __half22float2(*(const __half2*)&t2.y);
      a0 = __fmaf_rn(r2.x, __fmaf_rn(f2, b2.y, b2.x), a0);
      a1 = __fmaf_rn(r2.y, __fmaf_rn(f2, c2.y, c2.x), a1);
    }
    {
      float2 b3 = __half22float2(*(const __half2*)&t3.x);
      float2 c3 = __half22float2(*(const __half2*)&t3.y);
      a0 = __fmaf_rn(r3.x, __fmaf_rn(f3, b3.y, b3.x), a0);
      a1 = __fmaf_rn(r3.y, __fmaf_rn(f3, c3.y, c3.x), a1);
    }
  }
  for (; j < j1; ++j) {
    int2 p = items[j];
    int sx = __builtin_amdgcn_readfirstlane(p.x);
    int sy = __builtin_amdgcn_readfirstlane(p.y);
    const uint2* tp = Th + ((size_t)(sy >> 16) << 6);
    const __half* rp = rfh + ((size_t)(sx & 0xffff) << 7);
    uint2 tv = tp[l];
    unsigned qq = *(const unsigned*)(rp + 2 * l);
    float fr = __half2float(__ushort_as_half((unsigned short)sy));
    float2 rv = __half22float2(*(const __half2*)&qq);
    float2 bb = __half22float2(*(const __half2*)&tv.x);
    float2 cc = __half22float2(*(const __half2*)&tv.y);
    a0 = __fmaf_rn(rv.x, __fmaf_rn(fr, bb.y, bb.x), a0);
    a1 = __fmaf_rn(rv.y, __fmaf_rn(fr, cc.y, cc.x), a1);
  }
  float2 o; o.x = a0; o.y = a1;
  *(float2*)&agg[((size_t)n << 7) + 2 * l] = o;
}

// ---------------------------------------------------------------------------
extern "C" void kernel_launch(void* const* d_in, const int* in_sizes, int n_in,
                              void* d_out, int out_size, void* d_ws, size_t ws_size,
                              hipStream_t stream) {
  const float* r     = (const float*)d_in[0];
  const float* e     = (const float*)d_in[1];
  const int*   a     = (const int*)d_in[2];
  const float* W_df1 = (const float*)d_in[3];
  const float* b_df1 = (const float*)d_in[4];
  const float* W_df2 = (const float*)d_in[5];
  const float* b_df2 = (const float*)d_in[6];
  const float* W_af  = (const float*)d_in[7];
  const float* W_d1  = (const float*)d_in[8];
  const float* b_d1  = (const float*)d_in[9];
  const float* W_d2  = (const float*)d_in[10];
  const float* b_d2  = (const float*)d_in[11];

  const int N = in_sizes[0] / NAB;
  const int E = in_sizes[1];
  const int H = 2 * E;
  const int NB = (N + BN - 1) / BN;   // 391 buckets

  // workspace layout (~58 MB). shared region: items [scatter->pull], then
  // t1 [gemm->gemm] — strictly sequential lifetimes.
  char* base = (char*)d_ws;
  size_t items_bytes = (size_t)H * sizeof(int2);        // 25.6 MB exact
  size_t t1_bytes = (size_t)N * NAB * sizeof(float);    // 25.6 MB
  size_t shared_bytes = items_bytes > t1_bytes ? items_bytes : t1_bytes;
  int2*   items  = (int2*)base;                         // first life
  float*  t1     = (float*)base;                        // second life
  float*  agg    = (float*)(base + shared_bytes);       // N*128 fp32
  __half* rfh    = (__half*)(agg + (size_t)N * NAB);    // N*128 fp16
  uint2*  Th     = (uint2*)(rfh + (size_t)N * NAB);     // (TK-1)*64*8B
  int*    hist   = (int*)(Th + (size_t)(TK - 1) * 64);  // NB*NBLK (400 KB)
  int*    btot   = hist + (size_t)NB * NBLK;            // NB
  int*    bbase  = btot + NB;                           // NB
  int*    nstart = bbase + NB;                          // N
  int*    nend   = nstart + N;                          // N

  const int gblocks = (N + 31) / 32;

  // 1) fp16 (base,delta) ef lerp table
  build_tp<<<TK - 1, 128, 0, stream>>>(W_df1, b_df1, W_df2, b_df2, Th);
  // 2) rfh = fp16(r @ W_af) — fused cast epilogue
  gemm128<<<gblocks, 128, 0, stream>>>(r, W_af, nullptr, rfh, N, 2);
  // 3) radix P1: per-(bucket, block) histogram
  hist_pass<<<NBLK, TPB, 0, stream>>>((const int2*)a, hist, E, NB);
  // 4) scans: per-bucket block offsets + bucket bases
  scan_bucket<<<NB, NBLK, 0, stream>>>(hist, btot);
  scan_bbase<<<1, 512, 0, stream>>>(btot, bbase, NB);
  // 5) radix P2: deterministic scatter into pre-reserved ranges (no atomics)
  scatter_pass<<<NBLK, TPB, 0, stream>>>((const int2*)a, e, hist, bbase, items, E, NB);
  // 6) per-bucket counting sort -> node-ordered items + CSR
  local_sort<<<NB, 256, 0, stream>>>(bbase, btot, items, nstart, nend, N);
  // 7) wave-per-node pull (SGPR gather bases, fp16 rf, fp16 base/delta table)
  pull_kernel<<<(N + 3) / 4, 256, 0, stream>>>(nstart, nend, items, rfh, Th, agg, N);
  // 8) t1 = ssp(agg @ W_d1 + b_d1)
  gemm128<<<gblocks, 128, 0, stream>>>(agg, W_d1, b_d1, t1, N, 1);
  // 9) out = t1 @ W_d2 + b_d2
  gemm128<<<gblocks, 128, 0, stream>>>(t1, W_d2, b_d2, d_out, N, 0);
}